// Round 13
// baseline (308.490 us; speedup 1.0000x reference)
//
#include <hip/hip_runtime.h>

#define BB 2
#define NN 256
#define DD 512
#define HH 8

// 0.125 * log2(e): scores are kept in the exp2 domain end-to-end.
#define SCL 0.18033688f

typedef float f4raw __attribute__((ext_vector_type(4)));

__device__ __forceinline__ float dot4(float4 a, float4 b) {
    return a.x*b.x + a.y*b.y + a.z*b.z + a.w*b.w;
}

__device__ __forceinline__ float4 f4fma(float s, float4 a, float4 acc) {
    acc.x += s * a.x; acc.y += s * a.y; acc.z += s * a.z; acc.w += s * a.w;
    return acc;
}

__device__ __forceinline__ float4 f4mul(float s, float4 a) {
    a.x *= s; a.y *= s; a.z *= s; a.w *= s; return a;
}

__device__ __forceinline__ float4 f4add(float4 a, float4 b) {
    a.x += b.x; a.y += b.y; a.z += b.z; a.w += b.w; return a;
}

__device__ __forceinline__ void gload_lds16(const void* g, void* l) {
    __builtin_amdgcn_global_load_lds(
        (const __attribute__((address_space(1))) unsigned int*)g,
        (__attribute__((address_space(3))) unsigned int*)l, 16, 0, 0);
}

// Stage 8 rows x 512 floats global->LDS with per-row XOR swizzle.
// 4-wave cooperative (qkp): dest linear, source pre-swizzled (m173).
__device__ __forceinline__ void stage_swz(const char* rowbase, float4* dst, int w, int lane) {
    #pragma unroll
    for (int j = 0; j < 4; ++j) {
        const int f0 = w * 256 + j * 64;
        const int y = f0 >> 7;
        const int c = (f0 & 127) + lane;
        gload_lds16(rowbase + (size_t)y * 2048 + ((size_t)(c ^ y) << 4), &dst[f0]);
    }
}

// Wave-PRIVATE G staging, 1 row/wave: wave w stages row (tt*4 + w).
// 2 gload_lds per wave per tile; swizzle key = w.
__device__ __forceinline__ void stageG1(const char* Grow, int tt, int w, int lane, float4* dst) {
    const char* src = Grow + (size_t)(tt * 4 + w) * 2048;
    #pragma unroll
    for (int j = 0; j < 2; ++j) {
        const int c = j * 64 + lane;
        gload_lds16(src + ((size_t)(c ^ w) << 4), &dst[j * 64]);
    }
}

// ---------------- kProj: 3 linear layers, O = X @ W^T + b -----------------
// grid 768 = 3 proj x 16 rowtiles x 16 coltiles (32x32 tile); block 64 (1 wave)
__global__ __launch_bounds__(64) void kProj(
    const float* __restrict__ in_,
    const float* __restrict__ w0, const float* __restrict__ b0,
    const float* __restrict__ w1, const float* __restrict__ b1,
    const float* __restrict__ w2, const float* __restrict__ b2,
    float* __restrict__ o0, float* __restrict__ o1, float* __restrict__ o2)
{
    __shared__ float4 xs[2][32 * 5];
    __shared__ float4 ws[2][32 * 5];

    const int t = threadIdx.x;
    const int blk = blockIdx.x;
    const int proj = blk >> 8;
    const int rem = blk & 255;
    const int row0 = (rem >> 4) * 32;
    const int col0 = (rem & 15) * 32;

    const float* W; const float* Bp; float* O;
    if (proj == 0)      { W = w0; Bp = b0; O = o0; }
    else if (proj == 1) { W = w1; Bp = b1; O = o1; }
    else                { W = w2; Bp = b2; O = o2; }

    const float4* X4 = (const float4*)in_ + (size_t)row0 * 128;
    const float4* W4 = (const float4*)W  + (size_t)col0 * 128;

    const int sr = t >> 2, se = t & 3;
    const int ty = t >> 3, tx = t & 7;

    float4 rx0 = X4[(size_t)sr * 128 + se];
    float4 rx1 = X4[(size_t)(sr + 16) * 128 + se];
    float4 rw0 = W4[(size_t)sr * 128 + se];
    float4 rw1 = W4[(size_t)(sr + 16) * 128 + se];
    xs[0][sr * 5 + se] = rx0;  xs[0][(sr + 16) * 5 + se] = rx1;
    ws[0][sr * 5 + se] = rw0;  ws[0][(sr + 16) * 5 + se] = rw1;

    float acc[4][4] = {};

    for (int q = 0; q < 32; ++q) {
        __syncthreads();
        const int cur = q & 1;
        if (q < 31) {
            const int ko = (q + 1) * 4;
            rx0 = X4[(size_t)sr * 128 + ko + se];
            rx1 = X4[(size_t)(sr + 16) * 128 + ko + se];
            rw0 = W4[(size_t)sr * 128 + ko + se];
            rw1 = W4[(size_t)(sr + 16) * 128 + ko + se];
        }
        const float4* xb = xs[cur];
        const float4* wb = ws[cur];
        #pragma unroll
        for (int e4 = 0; e4 < 4; ++e4) {
            float4 xr[4], wc[4];
            #pragma unroll
            for (int i = 0; i < 4; ++i) xr[i] = xb[(ty + 8 * i) * 5 + e4];
            #pragma unroll
            for (int j = 0; j < 4; ++j) wc[j] = wb[(tx + 8 * j) * 5 + e4];
            #pragma unroll
            for (int i = 0; i < 4; ++i)
                #pragma unroll
                for (int j = 0; j < 4; ++j)
                    acc[i][j] += dot4(xr[i], wc[j]);
        }
        if (q < 31) {
            const int nxt = cur ^ 1;
            xs[nxt][sr * 5 + se] = rx0;  xs[nxt][(sr + 16) * 5 + se] = rx1;
            ws[nxt][sr * 5 + se] = rw0;  ws[nxt][(sr + 16) * 5 + se] = rw1;
        }
    }

    float bb[4];
    #pragma unroll
    for (int j = 0; j < 4; ++j) bb[j] = Bp[col0 + tx + 8 * j];
    #pragma unroll
    for (int i = 0; i < 4; ++i) {
        const int orow = row0 + ty + 8 * i;
        #pragma unroll
        for (int j = 0; j < 4; ++j)
            O[(size_t)orow * DD + col0 + tx + 8 * j] = acc[i][j] + bb[j];
    }
}

// ---------------- kQS: fused kQkp (blocks 0..2047) + kSk (2048..4095) -----
__global__ __launch_bounds__(256) void kQS(
    const float* __restrict__ q, const float* __restrict__ wrk,
    const float* __restrict__ k, const unsigned char* __restrict__ mask,
    float* __restrict__ qkp, float* __restrict__ sk)
{
    __shared__ float sm[4680];   // kSk: qs 8*65 + ks 64*65; kQkp: 512
    const int t = threadIdx.x;
    const int blk0 = blockIdx.x;

    if (blk0 < 2048) {
        // ---- qkp[row,h,e] = sum_d q[row,h*64+d]*wrk[h*64+d,e] ----
        float* qs = sm;
        const int rowg = blk0 >> 5;
        const int h = (blk0 >> 2) & 7;
        const int eq = blk0 & 3;
        const int row0 = rowg * 8;
        {
            const int r = t >> 5, d2 = (t & 31) * 2;
            const float2 tmp = *(const float2*)(q + (size_t)(row0 + r) * DD + h * 64 + d2);
            qs[r * 64 + d2] = tmp.x; qs[r * 64 + d2 + 1] = tmp.y;
        }
        __syncthreads();
        const int e = eq * 128 + (t & 127);
        const int rp = (t >> 7) * 4;
        const float* wcol = wrk + (size_t)(h * 64) * DD + e;
        float a0 = 0, a1 = 0, a2 = 0, a3 = 0;
        #pragma unroll 8
        for (int d = 0; d < 64; ++d) {
            const float wv = wcol[(size_t)d * DD];
            a0 += qs[(rp + 0) * 64 + d] * wv;
            a1 += qs[(rp + 1) * 64 + d] * wv;
            a2 += qs[(rp + 2) * 64 + d] * wv;
            a3 += qs[(rp + 3) * 64 + d] * wv;
        }
        qkp[((size_t)(row0 + rp + 0) * HH + h) * DD + e] = a0;
        qkp[((size_t)(row0 + rp + 1) * HH + h) * DD + e] = a1;
        qkp[((size_t)(row0 + rp + 2) * HH + h) * DD + e] = a2;
        qkp[((size_t)(row0 + rp + 3) * HH + h) * DD + e] = a3;
    } else {
        // ---- sk = SCL*(q.k) + mask, exp2 domain ----
        const int blk = blk0 - 2048;
        float* qs = sm;              // 8*65
        float* ks = sm + 8 * 65;     // 64*65
        const int b  = blk >> 10;
        const int h  = (blk >> 7) & 7;
        const int xt = (blk >> 2) & 31;
        const int yt = blk & 3;
        const int x0 = xt * 8, y0 = yt * 64;
        {
            const int r = t >> 5, d2 = (t & 31) * 2;
            const float2 tmp = *(const float2*)(q + (size_t)(b * NN + x0 + r) * DD + h * 64 + d2);
            qs[r * 65 + d2] = tmp.x; qs[r * 65 + d2 + 1] = tmp.y;
        }
        #pragma unroll
        for (int j = 0; j < 8; ++j) {
            const int f = t + 256 * j;
            const int r = f >> 5, d2 = (f & 31) * 2;
            const float2 tmp = *(const float2*)(k + (size_t)(b * NN + y0 + r) * DD + h * 64 + d2);
            ks[r * 65 + d2] = tmp.x; ks[r * 65 + d2 + 1] = tmp.y;
        }
        __syncthreads();
        const int xi = t >> 5, yg = t & 31;
        float a0 = 0, a1 = 0;
        #pragma unroll 8
        for (int d = 0; d < 64; ++d) {
            const float qv = qs[xi * 65 + d];
            a0 += qv * ks[(yg * 2 + 0) * 65 + d];
            a1 += qv * ks[(yg * 2 + 1) * 65 + d];
        }
        a0 *= SCL; a1 *= SCL;
        const unsigned char* mrow = mask + (size_t)(b * NN + x0 + xi) * NN;
        const int gy = y0 + yg * 2;
        if (mrow[gy + 0]) a0 = -1e9f;
        if (mrow[gy + 1]) a1 = -1e9f;
        float2 st; st.x = a0; st.y = a1;
        *(float2*)(sk + ((size_t)(b * NN + x0 + xi) * HH + h) * NN + gy) = st;
    }
}

// ---------------- kC: split-K4, 1 row/wave tiles, counted-vmcnt ----------
// grid 2048 = (b*N) x 4 parts; block 256 = 4 waves; 16 tiles of 4 y-rows.
// Wave w owns row w of each tile (2 gload_lds/tile). LDS 36 KB ->
// 4 blocks/CU (16 waves). qkp in LDS; no in-loop barriers; vmcnt(2).
__global__ __launch_bounds__(256, 2) void kC(
    const float* __restrict__ G, const float* __restrict__ sk,
    const float* __restrict__ qkp, const float* __restrict__ v,
    float* __restrict__ pg, float* __restrict__ pxv,
    float* __restrict__ pm, float* __restrict__ pl)
{
    __shared__ float4 Gdb[2][4][128];   // 16 KB; merge scratch rA in epilogue
    __shared__ float4 qk4[1024];        // 16 KB; xv merge scratch in epilogue
    __shared__ float  sk_lds[512];      // [ry 0..63][h 0..7]; ml overlay later
    __shared__ float  s_st[512];        // scores [ry][h]

    const int t = threadIdx.x;
    const int lane = t & 63;
    const int w = t >> 6;
    const int blk = blockIdx.x;
    const int part = blk & 3;
    const int bid = blk >> 2;
    const int b = bid >> 8;
    const int ybase = part * 64;

    const int s_ = lane & 15;
    const int g  = lane >> 4;
    const int h0_ = 2 * g, h1_ = h0_ + 1;

    const char* Grow = (const char*)(G + (size_t)bid * NN * DD) + (size_t)ybase * 2048;
    const float* skb = sk + (size_t)bid * HH * NN;
    const float4* vb4 = (const float4*)(v + (size_t)(b * NN) * DD);

    // ---- prologue: qkp stage, sk regs, G tile0, counted wait ----
    const int f0p = 2 * t, f1p = 2 * t + 1;
    const float skv0 = skb[(f0p & 7) * NN + ybase + (f0p >> 3)];
    const float skv1 = skb[(f1p & 7) * NN + ybase + (f1p >> 3)];
    stage_swz((const char*)(qkp + (size_t)bid * HH * DD), qk4, w, lane);
    stageG1(Grow, 0, w, lane, &Gdb[0][w][0]);
    asm volatile("s_waitcnt vmcnt(2)" ::: "memory");
    __builtin_amdgcn_sched_barrier(0);
    sk_lds[f0p] = skv0;
    sk_lds[f1p] = skv1;
    __syncthreads();   // compiler drains vmcnt: tile0 + qkp ready

    float4 gA[8], gB[8];
    float m[8], l[8];
    #pragma unroll
    for (int h = 0; h < 8; ++h) {
        gA[h] = make_float4(0, 0, 0, 0);
        gB[h] = make_float4(0, 0, 0, 0);
        m[h] = -3e38f; l[h] = 0.f;
    }
    float4 xva = {0, 0, 0, 0}, xvb = {0, 0, 0, 0};

    int cb = 0;
    #pragma unroll 1
    for (int tt = 0; tt < 16; ++tt) {
        const int gy = ybase + tt * 4 + w;
        const int ry = tt * 4 + w;

        // v loads FIRST (so vmcnt(2) retires them with stage(tt))
        const float4 va0 = vb4[(size_t)gy * 128 + 32 * g + s_];
        const float4 vb0 = vb4[(size_t)gy * 128 + 32 * g + 16 + s_];
        __builtin_amdgcn_sched_barrier(0);
        if (tt < 15)
            stageG1(Grow, tt + 1, w, lane, &Gdb[cb ^ 1][w][0]);
        if (tt < 15) {
            asm volatile("s_waitcnt vmcnt(2)" ::: "memory");
        } else {
            asm volatile("s_waitcnt vmcnt(0)" ::: "memory");
        }
        __builtin_amdgcn_sched_barrier(0);

        const float4* gb = &Gdb[cb][w][0];

        // ---- scores: group g -> (1 row) x (h0_,h1_) ----
        {
            float a00 = 0, a01 = 0;
            #pragma unroll
            for (int i = 0; i < 8; ++i) {
                const int e4 = i * 16 + s_;
                const float4 g0 = gb[(e4 ^ w)];
                a00 += dot4(g0, qk4[h0_ * 128 + (e4 ^ h0_)]);
                a01 += dot4(g0, qk4[h1_ * 128 + (e4 ^ h1_)]);
            }
            #pragma unroll
            for (int mm = 1; mm < 16; mm <<= 1) {
                a00 += __shfl_xor(a00, mm); a01 += __shfl_xor(a01, mm);
            }
            if (s_ < 2) {
                const float val = (s_ == 0) ? a00 : a01;
                const int h = h0_ + s_;
                s_st[ry * 8 + h] = val * SCL + sk_lds[ry * 8 + h];
            }
        }

        // ---- same-wave readback ----
        const float4 sva = *(const float4*)&s_st[ry * 8];
        const float4 svb = *(const float4*)&s_st[ry * 8 + 4];
        const float s0[8] = {sva.x, sva.y, sva.z, sva.w, svb.x, svb.y, svb.z, svb.w};

        const float4 gr0a = gb[(lane ^ w)];
        const float4 gr0b = gb[((lane + 64) ^ w)];

        float p0a = 0, rsa = 1, p0b = 0, rsb = 1;
        #pragma unroll
        for (int h = 0; h < 8; ++h) {
            const float mn = fmaxf(m[h], s0[h]);
            const float rs = exp2f(m[h] - mn);
            const float p0 = exp2f(s0[h] - mn);
            m[h] = mn;
            l[h] = l[h] * rs + p0;
            gA[h] = f4fma(p0, gr0a, f4mul(rs, gA[h]));
            gB[h] = f4fma(p0, gr0b, f4mul(rs, gB[h]));
            if (h == h0_) { p0a = p0; rsa = rs; }
            if (h == h1_) { p0b = p0; rsb = rs; }
        }
        xva = f4fma(p0a, va0, f4mul(rsa, xva));
        xvb = f4fma(p0b, vb0, f4mul(rsb, xvb));
        cb ^= 1;
    }

    // ---- epilogue: merge 4 wave partials (sequential publish) ----
    asm volatile("s_waitcnt vmcnt(0)" ::: "memory");
    __syncthreads();
    float* ml = sk_lds;   // overlay (sk_lds dead)
    if (lane == 0) {
        #pragma unroll
        for (int h = 0; h < 8; ++h) { ml[w * 16 + h] = m[h]; ml[w * 16 + 8 + h] = l[h]; }
    }
    __syncthreads();

    float ea = 1.f, eb = 1.f;
    float Mv[8], Lv[8];
    #pragma unroll
    for (int h = 0; h < 8; ++h) {
        const float q0 = ml[h], q1 = ml[16 + h], q2 = ml[32 + h], q3 = ml[48 + h];
        const float Mh = fmaxf(fmaxf(q0, q1), fmaxf(q2, q3));
        const float Lh = exp2f(q0 - Mh) * ml[8 + h]  + exp2f(q1 - Mh) * ml[24 + h]
                       + exp2f(q2 - Mh) * ml[40 + h] + exp2f(q3 - Mh) * ml[56 + h];
        Mv[h] = Mh; Lv[h] = Lh;
        const float e = exp2f(m[h] - Mh);
        gA[h] = f4mul(e, gA[h]);
        gB[h] = f4mul(e, gB[h]);
        if (h == h0_) ea = e;
        if (h == h1_) eb = e;
    }
    xva = f4mul(ea, xva);
    xvb = f4mul(eb, xvb);

    float4* rA = &Gdb[0][0][0];        // 1024 f4: one wave's full partial
    float4* xs_ = qk4;                 // qkp dead: xv scratch (512 f4)
    xs_[w * 128 + 32 * g + s_] = xva;
    xs_[w * 128 + 32 * g + 16 + s_] = xvb;

    // sequential merge: w3 -> w2 -> w1 -> w0
    #pragma unroll 1
    for (int r = 3; r >= 1; --r) {
        __syncthreads();
        if (w == r) {
            #pragma unroll
            for (int h = 0; h < 8; ++h) { rA[h * 128 + lane] = gA[h]; rA[h * 128 + 64 + lane] = gB[h]; }
        }
        __syncthreads();
        if (w == r - 1) {
            #pragma unroll
            for (int h = 0; h < 8; ++h) {
                gA[h] = f4add(gA[h], rA[h * 128 + lane]);
                gB[h] = f4add(gB[h], rA[h * 128 + 64 + lane]);
            }
        }
    }

    if (w == 0) {
        float4* pgb = (float4*)pg + (size_t)blk * 1024;
        #pragma unroll
        for (int h = 0; h < 8; ++h) {
            pgb[h * 128 + lane] = gA[h];
            pgb[h * 128 + 64 + lane] = gB[h];
        }
        float4 xa = f4add(f4add(xs_[32 * g + s_],            xs_[128 + 32 * g + s_]),
                          f4add(xs_[256 + 32 * g + s_],      xs_[384 + 32 * g + s_]));
        float4 xb = f4add(f4add(xs_[32 * g + 16 + s_],       xs_[128 + 32 * g + 16 + s_]),
                          f4add(xs_[256 + 32 * g + 16 + s_], xs_[384 + 32 * g + 16 + s_]));
        float4* pxb = (float4*)pxv + (size_t)blk * 128;
        pxb[32 * g + s_] = xa;
        pxb[32 * g + 16 + s_] = xb;
        if (lane == 0) {
            #pragma unroll
            for (int h = 0; h < 8; ++h) { pm[blk * 8 + h] = Mv[h]; pl[blk * 8 + h] = Lv[h]; }
        }
    }
}

// ---------------- kM: merge 4 partials + wrv GEMV epilogue ----------------
// grid 1024 = bid x 2 output-halves; block 256 (exp2 domain)
__global__ __launch_bounds__(256) void kM(
    const float* __restrict__ pg, const float* __restrict__ pxv,
    const float* __restrict__ pm, const float* __restrict__ pl,
    const float* __restrict__ wrv, const float* __restrict__ brv,
    float* __restrict__ om)
{
    __shared__ float4 gc[512];
    __shared__ float xvs[256];
    __shared__ float wexp[16], Ls[4];
    const int t = threadIdx.x;
    const int blk = blockIdx.x;
    const int bid = blk >> 1;
    const int half = blk & 1;
    const int h0 = half * 4;
    __shared__ float mlds[16], llds[16];
    if (t < 16) {
        const int i = t >> 2, hh = t & 3;
        mlds[t] = pm[bid * 32 + i * 8 + h0 + hh];
        llds[t] = pl[bid * 32 + i * 8 + h0 + hh];
    }
    __syncthreads();
    if (t < 4) {
        float M = mlds[t];
        #pragma unroll
        for (int i = 1; i < 4; ++i) M = fmaxf(M, mlds[i * 4 + t]);
        float L = 0;
        #pragma unroll
        for (int i = 0; i < 4; ++i) {
            const float wv = exp2f(mlds[i * 4 + t] - M);
            wexp[i * 4 + t] = wv;
            L += wv * llds[i * 4 + t];
        }
        Ls[t] = L;
    }
    __syncthreads();
    const int c4 = t & 127;
    #pragma unroll
    for (int r = 0; r < 2; ++r) {
        const int hh = (t >> 7) * 2 + r;
        float4 acc = {0, 0, 0, 0};
        #pragma unroll
        for (int i = 0; i < 4; ++i) {
            const float wv = wexp[i * 4 + hh];
            const float4 g = ((const float4*)pg)[((size_t)bid * 4 + i) * 1024 + (size_t)(h0 + hh) * 128 + c4];
            acc.x += wv * g.x; acc.y += wv * g.y; acc.z += wv * g.z; acc.w += wv * g.w;
        }
        gc[hh * 128 + c4] = acc;
    }
    {
        const int hh = t >> 6;
        float s = 0;
        #pragma unroll
        for (int i = 0; i < 4; ++i)
            s += wexp[i * 4 + hh] * pxv[((size_t)bid * 4 + i) * DD + half * 256 + t];
        xvs[t] = s;
    }
    __syncthreads();
    const int o = half * 256 + t;
    const int hl = t >> 6;
    const float4* wr4 = (const float4*)(wrv + (size_t)o * DD);
    float acc = 0;
    #pragma unroll 4
    for (int e4 = 0; e4 < 128; ++e4) acc += dot4(wr4[e4], gc[hl * 128 + e4]);
    om[(size_t)bid * DD + o] = (xvs[t] + acc) / Ls[hl] + brv[o];
}

// ---------------- kE ----------------
__global__ __launch_bounds__(256) void kE(
    const float* __restrict__ xl, const float* __restrict__ xr,
    float* __restrict__ ng)
{
    const int t = threadIdx.x;
    const int blk = blockIdx.x;
    const int bid = blk >> 2;
    const int yc = blk & 3;
    const int b = bid >> 8;
    const int o4 = t & 127;
    const int yh = t >> 7;
    const float4 left = ((const float4*)xl)[(size_t)bid * 128 + o4];
    const float4* xr4 = (const float4*)xr + (size_t)b * NN * 128;
    f4raw* out4 = (f4raw*)ng + (size_t)bid * NN * 128;
    for (int y = yc * 64 + yh; y < yc * 64 + 64; y += 2) {
        const float4 rr = xr4[y * 128 + o4];
        f4raw s;
        s.x = left.x + rr.x; s.y = left.y + rr.y;
        s.z = left.z + rr.z; s.w = left.w + rr.w;
        __builtin_nontemporal_store(s, &out4[y * 128 + o4]);
    }
}

extern "C" void kernel_launch(void* const* d_in, const int* in_sizes, int n_in,
                              void* d_out, int out_size, void* d_ws, size_t ws_size,
                              hipStream_t stream)
{
    (void)in_sizes; (void)n_in; (void)out_size; (void)ws_size;
    const float* x    = (const float*)d_in[0];
    const float* G    = (const float*)d_in[1];
    const unsigned char* mask = (const unsigned char*)d_in[2];
    const float* wq  = (const float*)d_in[3];  const float* bq  = (const float*)d_in[4];
    const float* wk  = (const float*)d_in[5];  const float* bk  = (const float*)d_in[6];
    const float* wv  = (const float*)d_in[7];  const float* bv  = (const float*)d_in[8];
    const float* wo  = (const float*)d_in[9];  const float* bo  = (const float*)d_in[10];
    const float* wl  = (const float*)d_in[11]; const float* bl  = (const float*)d_in[12];
    const float* wr  = (const float*)d_in[13]; const float* br  = (const float*)d_in[14];
    const float* wrk = (const float*)d_in[15]; /* brk unused: softmax-invariant */
    const float* wrv = (const float*)d_in[17]; const float* brv = (const float*)d_in[18];

    float* out  = (float*)d_out;
    float* fout = out;                          // [B,N,D]
    float* ng   = out + (size_t)BB * NN * DD;   // [B,N,N,D]

    const size_t ng_f  = (size_t)BB * NN * NN * DD;
    const size_t row_f = (size_t)BB * NN * DD;
    const size_t total = row_f * 52 + 32768;
    float* base = ng + ng_f - total;
    float* q    = base;
    float* k    = q   + row_f;
    float* vv_  = k   + row_f;
    float* qkp  = vv_ + row_f;          // row_f * 8
    float* skp  = qkp + row_f * 8;      // row_f * 4
    float* pg   = skp + row_f * 4;      // row_f * 32
    float* pxv  = pg  + row_f * 32;     // row_f * 4
    float* pm   = pxv + row_f * 4;      // 16384
    float* pl   = pm  + 16384;          // 16384
    float* om   = pl  + 16384;          // row_f
    float* xl = (float*)d_ws;
    float* xr = xl + row_f;

    kProj<<<768, 64, 0, stream>>>(x, wq, bq, wk, bk, wv, bv, q, k, vv_);
    kQS  <<<4096, 256, 0, stream>>>(q, wrk, k, mask, qkp, skp);
    kC   <<<2048, 256, 0, stream>>>(G, skp, qkp, vv_, pg, pxv, pm, pl);
    kM   <<<1024, 256, 0, stream>>>(pg, pxv, pm, pl, wrv, brv, om);
    kProj<<<768, 64, 0, stream>>>(om, wo, bo, wl, bl, wr, br, fout, xl, xr);
    kE   <<<2048, 256, 0, stream>>>(xl, xr, ng);
}

// Round 14
// 305.869 us; speedup vs baseline: 1.0086x; 1.0086x over previous
//
#include <hip/hip_runtime.h>

#define BB 2
#define NN 256
#define DD 512
#define HH 8

// 0.125 * log2(e): scores are kept in the exp2 domain end-to-end.
#define SCL 0.18033688f

typedef float f4raw __attribute__((ext_vector_type(4)));

__device__ __forceinline__ float dot4(float4 a, float4 b) {
    return a.x*b.x + a.y*b.y + a.z*b.z + a.w*b.w;
}

__device__ __forceinline__ float4 f4fma(float s, float4 a, float4 acc) {
    acc.x += s * a.x; acc.y += s * a.y; acc.z += s * a.z; acc.w += s * a.w;
    return acc;
}

__device__ __forceinline__ float4 f4mul(float s, float4 a) {
    a.x *= s; a.y *= s; a.z *= s; a.w *= s; return a;
}

__device__ __forceinline__ float4 f4add(float4 a, float4 b) {
    a.x += b.x; a.y += b.y; a.z += b.z; a.w += b.w; return a;
}

__device__ __forceinline__ void gload_lds16(const void* g, void* l) {
    __builtin_amdgcn_global_load_lds(
        (const __attribute__((address_space(1))) unsigned int*)g,
        (__attribute__((address_space(3))) unsigned int*)l, 16, 0, 0);
}

// Stage 8 rows x 512 floats global->LDS with per-row XOR swizzle.
// 4-wave cooperative (qkp): dest linear, source pre-swizzled (m173).
__device__ __forceinline__ void stage_swz(const char* rowbase, float4* dst, int w, int lane) {
    #pragma unroll
    for (int j = 0; j < 4; ++j) {
        const int f0 = w * 256 + j * 64;
        const int y = f0 >> 7;
        const int c = (f0 & 127) + lane;
        gload_lds16(rowbase + (size_t)y * 2048 + ((size_t)(c ^ y) << 4), &dst[f0]);
    }
}

// ---------------- kProj: 3 linear layers, O = X @ W^T + b -----------------
// grid 768 = 3 proj x 16 rowtiles x 16 coltiles (32x32 tile); block 64 (1 wave)
__global__ __launch_bounds__(64) void kProj(
    const float* __restrict__ in_,
    const float* __restrict__ w0, const float* __restrict__ b0,
    const float* __restrict__ w1, const float* __restrict__ b1,
    const float* __restrict__ w2, const float* __restrict__ b2,
    float* __restrict__ o0, float* __restrict__ o1, float* __restrict__ o2)
{
    __shared__ float4 xs[2][32 * 5];
    __shared__ float4 ws[2][32 * 5];

    const int t = threadIdx.x;
    const int blk = blockIdx.x;
    const int proj = blk >> 8;
    const int rem = blk & 255;
    const int row0 = (rem >> 4) * 32;
    const int col0 = (rem & 15) * 32;

    const float* W; const float* Bp; float* O;
    if (proj == 0)      { W = w0; Bp = b0; O = o0; }
    else if (proj == 1) { W = w1; Bp = b1; O = o1; }
    else                { W = w2; Bp = b2; O = o2; }

    const float4* X4 = (const float4*)in_ + (size_t)row0 * 128;
    const float4* W4 = (const float4*)W  + (size_t)col0 * 128;

    const int sr = t >> 2, se = t & 3;
    const int ty = t >> 3, tx = t & 7;

    float4 rx0 = X4[(size_t)sr * 128 + se];
    float4 rx1 = X4[(size_t)(sr + 16) * 128 + se];
    float4 rw0 = W4[(size_t)sr * 128 + se];
    float4 rw1 = W4[(size_t)(sr + 16) * 128 + se];
    xs[0][sr * 5 + se] = rx0;  xs[0][(sr + 16) * 5 + se] = rx1;
    ws[0][sr * 5 + se] = rw0;  ws[0][(sr + 16) * 5 + se] = rw1;

    float acc[4][4] = {};

    for (int q = 0; q < 32; ++q) {
        __syncthreads();
        const int cur = q & 1;
        if (q < 31) {
            const int ko = (q + 1) * 4;
            rx0 = X4[(size_t)sr * 128 + ko + se];
            rx1 = X4[(size_t)(sr + 16) * 128 + ko + se];
            rw0 = W4[(size_t)sr * 128 + ko + se];
            rw1 = W4[(size_t)(sr + 16) * 128 + ko + se];
        }
        const float4* xb = xs[cur];
        const float4* wb = ws[cur];
        #pragma unroll
        for (int e4 = 0; e4 < 4; ++e4) {
            float4 xr[4], wc[4];
            #pragma unroll
            for (int i = 0; i < 4; ++i) xr[i] = xb[(ty + 8 * i) * 5 + e4];
            #pragma unroll
            for (int j = 0; j < 4; ++j) wc[j] = wb[(tx + 8 * j) * 5 + e4];
            #pragma unroll
            for (int i = 0; i < 4; ++i)
                #pragma unroll
                for (int j = 0; j < 4; ++j)
                    acc[i][j] += dot4(xr[i], wc[j]);
        }
        if (q < 31) {
            const int nxt = cur ^ 1;
            xs[nxt][sr * 5 + se] = rx0;  xs[nxt][(sr + 16) * 5 + se] = rx1;
            ws[nxt][sr * 5 + se] = rw0;  ws[nxt][(sr + 16) * 5 + se] = rw1;
        }
    }

    float bb[4];
    #pragma unroll
    for (int j = 0; j < 4; ++j) bb[j] = Bp[col0 + tx + 8 * j];
    #pragma unroll
    for (int i = 0; i < 4; ++i) {
        const int orow = row0 + ty + 8 * i;
        #pragma unroll
        for (int j = 0; j < 4; ++j)
            O[(size_t)orow * DD + col0 + tx + 8 * j] = acc[i][j] + bb[j];
    }
}

// ---------------- kQS: fused kQkp (blocks 0..2047) + kSk (2048..4095) -----
__global__ __launch_bounds__(256) void kQS(
    const float* __restrict__ q, const float* __restrict__ wrk,
    const float* __restrict__ k, const unsigned char* __restrict__ mask,
    float* __restrict__ qkp, float* __restrict__ sk)
{
    __shared__ float sm[4680];
    const int t = threadIdx.x;
    const int blk0 = blockIdx.x;

    if (blk0 < 2048) {
        float* qs = sm;
        const int rowg = blk0 >> 5;
        const int h = (blk0 >> 2) & 7;
        const int eq = blk0 & 3;
        const int row0 = rowg * 8;
        {
            const int r = t >> 5, d2 = (t & 31) * 2;
            const float2 tmp = *(const float2*)(q + (size_t)(row0 + r) * DD + h * 64 + d2);
            qs[r * 64 + d2] = tmp.x; qs[r * 64 + d2 + 1] = tmp.y;
        }
        __syncthreads();
        const int e = eq * 128 + (t & 127);
        const int rp = (t >> 7) * 4;
        const float* wcol = wrk + (size_t)(h * 64) * DD + e;
        float a0 = 0, a1 = 0, a2 = 0, a3 = 0;
        #pragma unroll 8
        for (int d = 0; d < 64; ++d) {
            const float wv = wcol[(size_t)d * DD];
            a0 += qs[(rp + 0) * 64 + d] * wv;
            a1 += qs[(rp + 1) * 64 + d] * wv;
            a2 += qs[(rp + 2) * 64 + d] * wv;
            a3 += qs[(rp + 3) * 64 + d] * wv;
        }
        qkp[((size_t)(row0 + rp + 0) * HH + h) * DD + e] = a0;
        qkp[((size_t)(row0 + rp + 1) * HH + h) * DD + e] = a1;
        qkp[((size_t)(row0 + rp + 2) * HH + h) * DD + e] = a2;
        qkp[((size_t)(row0 + rp + 3) * HH + h) * DD + e] = a3;
    } else {
        const int blk = blk0 - 2048;
        float* qs = sm;
        float* ks = sm + 8 * 65;
        const int b  = blk >> 10;
        const int h  = (blk >> 7) & 7;
        const int xt = (blk >> 2) & 31;
        const int yt = blk & 3;
        const int x0 = xt * 8, y0 = yt * 64;
        {
            const int r = t >> 5, d2 = (t & 31) * 2;
            const float2 tmp = *(const float2*)(q + (size_t)(b * NN + x0 + r) * DD + h * 64 + d2);
            qs[r * 65 + d2] = tmp.x; qs[r * 65 + d2 + 1] = tmp.y;
        }
        #pragma unroll
        for (int j = 0; j < 8; ++j) {
            const int f = t + 256 * j;
            const int r = f >> 5, d2 = (f & 31) * 2;
            const float2 tmp = *(const float2*)(k + (size_t)(b * NN + y0 + r) * DD + h * 64 + d2);
            ks[r * 65 + d2] = tmp.x; ks[r * 65 + d2 + 1] = tmp.y;
        }
        __syncthreads();
        const int xi = t >> 5, yg = t & 31;
        float a0 = 0, a1 = 0;
        #pragma unroll 8
        for (int d = 0; d < 64; ++d) {
            const float qv = qs[xi * 65 + d];
            a0 += qv * ks[(yg * 2 + 0) * 65 + d];
            a1 += qv * ks[(yg * 2 + 1) * 65 + d];
        }
        a0 *= SCL; a1 *= SCL;
        const unsigned char* mrow = mask + (size_t)(b * NN + x0 + xi) * NN;
        const int gy = y0 + yg * 2;
        if (mrow[gy + 0]) a0 = -1e9f;
        if (mrow[gy + 1]) a1 = -1e9f;
        float2 st; st.x = a0; st.y = a1;
        *(float2*)(sk + ((size_t)(b * NN + x0 + xi) * HH + h) * NN + gy) = st;
    }
}

// ---------------- kC: G-in-REGISTERS flash attention, split-K4 -----------
// grid 2048 = (b*N) x 4 parts; block 256 = 4 waves; 8 tiles of 8 y-rows.
// Wave w owns rows {2w,2w+1}: loads them straight to VGPRs (no LDS for G,
// no staging, no in-loop barriers). 16-lane group g owns heads {2g,2g+1}:
// dots its full rows vs LDS-broadcast qkp, FULL butterfly all-reduce gives
// every lane its group's 4 scores in regs (no score LDS round-trip).
// Each group accumulates g_agg for its 2 heads over its 8 owned slots.
__global__ __launch_bounds__(256) void kC(
    const float* __restrict__ G, const float* __restrict__ sk,
    const float* __restrict__ qkp, const float* __restrict__ v,
    float* __restrict__ pg, float* __restrict__ pxv,
    float* __restrict__ pm, float* __restrict__ pl)
{
    __shared__ float4 qk4[1024];   // qkp [8h][128] swizzled ^h; merge scratch later
    __shared__ float4 xvm[512];    // per-wave xv partials [w][h*16+s_]
    __shared__ float  sk_lds[512]; // [ry 0..63][h 0..7]; ml overlay later

    const int t = threadIdx.x;
    const int lane = t & 63;
    const int w = t >> 6;
    const int blk = blockIdx.x;
    const int part = blk & 3;
    const int bid = blk >> 2;
    const int b = bid >> 8;
    const int ybase = part * 64;

    const int s_ = lane & 15;
    const int g  = lane >> 4;
    const int h0_ = 2 * g, h1_ = h0_ + 1;
    const int yr0 = 2 * w, yr1 = yr0 + 1;

    const float4* Gb4 = (const float4*)(G + (size_t)bid * NN * DD);
    const float* skb = sk + (size_t)bid * HH * NN;
    const float4* vb4 = (const float4*)(v + (size_t)(b * NN) * DD);

    // ---- prologue: qkp -> LDS (staged), sk -> LDS ----
    const int f0p = 2 * t, f1p = 2 * t + 1;
    const float skv0 = skb[(f0p & 7) * NN + ybase + (f0p >> 3)];
    const float skv1 = skb[(f1p & 7) * NN + ybase + (f1p >> 3)];
    stage_swz((const char*)(qkp + (size_t)bid * HH * DD), qk4, w, lane);
    sk_lds[f0p] = skv0;
    sk_lds[f1p] = skv1;
    __syncthreads();   // drains vmcnt: qkp ready

    float4 gagg0[8], gagg1[8];
    #pragma unroll
    for (int i = 0; i < 8; ++i) {
        gagg0[i] = make_float4(0, 0, 0, 0);
        gagg1[i] = make_float4(0, 0, 0, 0);
    }
    float4 xv0 = {0, 0, 0, 0}, xv1 = {0, 0, 0, 0};
    float m0_ = -3e38f, m1_ = -3e38f, l0_ = 0.f, l1_ = 0.f;

    #pragma unroll 1
    for (int tt = 0; tt < 8; ++tt) {
        const int gy0 = ybase + tt * 8 + yr0;
        const int gy1 = gy0 + 1;
        const int ry0 = tt * 8 + yr0, ry1 = ry0 + 1;

        // G rows -> registers (16 dwordx4; group-replicated slot map)
        float4 g0[8], g1[8];
        #pragma unroll
        for (int i = 0; i < 8; ++i) g0[i] = Gb4[(size_t)gy0 * 128 + i * 16 + s_];
        #pragma unroll
        for (int i = 0; i < 8; ++i) g1[i] = Gb4[(size_t)gy1 * 128 + i * 16 + s_];
        // v fragments for this lane's 2 heads
        const float4 v00 = vb4[(size_t)gy0 * 128 + h0_ * 16 + s_];
        const float4 v01 = vb4[(size_t)gy0 * 128 + h1_ * 16 + s_];
        const float4 v10 = vb4[(size_t)gy1 * 128 + h0_ * 16 + s_];
        const float4 v11 = vb4[(size_t)gy1 * 128 + h1_ * 16 + s_];

        // partial dots vs broadcast qkp
        float a00 = 0, a01 = 0, a10 = 0, a11 = 0;
        #pragma unroll
        for (int i = 0; i < 8; ++i) {
            const int e4 = i * 16 + s_;
            const float4 q0 = qk4[h0_ * 128 + (e4 ^ h0_)];
            const float4 q1 = qk4[h1_ * 128 + (e4 ^ h1_)];
            a00 += dot4(g0[i], q0); a01 += dot4(g0[i], q1);
            a10 += dot4(g1[i], q0); a11 += dot4(g1[i], q1);
        }
        // FULL 16-lane all-reduce: every lane gets all 4 scores
        #pragma unroll
        for (int mm = 1; mm < 16; mm <<= 1) {
            a00 += __shfl_xor(a00, mm); a01 += __shfl_xor(a01, mm);
            a10 += __shfl_xor(a10, mm); a11 += __shfl_xor(a11, mm);
        }
        const float s00 = a00 * SCL + sk_lds[ry0 * 8 + h0_];
        const float s01 = a01 * SCL + sk_lds[ry0 * 8 + h1_];
        const float s10 = a10 * SCL + sk_lds[ry1 * 8 + h0_];
        const float s11 = a11 * SCL + sk_lds[ry1 * 8 + h1_];

        // online softmax for this lane's 2 heads
        const float mn0 = fmaxf(m0_, fmaxf(s00, s10));
        const float rs0 = exp2f(m0_ - mn0);
        const float p00 = exp2f(s00 - mn0), p10 = exp2f(s10 - mn0);
        m0_ = mn0; l0_ = l0_ * rs0 + p00 + p10;
        const float mn1 = fmaxf(m1_, fmaxf(s01, s11));
        const float rs1 = exp2f(m1_ - mn1);
        const float p01 = exp2f(s01 - mn1), p11 = exp2f(s11 - mn1);
        m1_ = mn1; l1_ = l1_ * rs1 + p01 + p11;

        // accumulate from registers
        #pragma unroll
        for (int i = 0; i < 8; ++i) {
            gagg0[i] = f4fma(p10, g1[i], f4fma(p00, g0[i], f4mul(rs0, gagg0[i])));
            gagg1[i] = f4fma(p11, g1[i], f4fma(p01, g0[i], f4mul(rs1, gagg1[i])));
        }
        xv0 = f4fma(p10, v10, f4fma(p00, v00, f4mul(rs0, xv0)));
        xv1 = f4fma(p11, v11, f4fma(p01, v01, f4mul(rs1, xv1)));
    }

    // ---- epilogue: merge 4 wave partials ----
    __syncthreads();
    float* ml = sk_lds;   // overlay (sk_lds dead)
    if (s_ == 0) {
        ml[w * 16 + h0_] = m0_;      ml[w * 16 + h1_] = m1_;
        ml[w * 16 + 8 + h0_] = l0_;  ml[w * 16 + 8 + h1_] = l1_;
    }
    __syncthreads();

    float M0, M1, L0, L1;
    {
        const float q0 = ml[h0_], q1 = ml[16 + h0_], q2 = ml[32 + h0_], q3 = ml[48 + h0_];
        M0 = fmaxf(fmaxf(q0, q1), fmaxf(q2, q3));
        L0 = exp2f(q0 - M0) * ml[8 + h0_]  + exp2f(q1 - M0) * ml[24 + h0_]
           + exp2f(q2 - M0) * ml[40 + h0_] + exp2f(q3 - M0) * ml[56 + h0_];
        const float r0 = ml[h1_], r1 = ml[16 + h1_], r2 = ml[32 + h1_], r3 = ml[48 + h1_];
        M1 = fmaxf(fmaxf(r0, r1), fmaxf(r2, r3));
        L1 = exp2f(r0 - M1) * ml[8 + h1_]  + exp2f(r1 - M1) * ml[24 + h1_]
           + exp2f(r2 - M1) * ml[40 + h1_] + exp2f(r3 - M1) * ml[56 + h1_];
    }
    const float e0 = exp2f(m0_ - M0), e1 = exp2f(m1_ - M1);
    #pragma unroll
    for (int i = 0; i < 8; ++i) {
        gagg0[i] = f4mul(e0, gagg0[i]);
        gagg1[i] = f4mul(e1, gagg1[i]);
    }
    xv0 = f4mul(e0, xv0); xv1 = f4mul(e1, xv1);

    xvm[w * 128 + h0_ * 16 + s_] = xv0;
    xvm[w * 128 + h1_ * 16 + s_] = xv1;

    float4* rA = qk4;   // qkp dead: merge scratch (1024 f4)
    // sequential merge: w3 -> w2 -> w1 -> w0
    #pragma unroll 1
    for (int r = 3; r >= 1; --r) {
        __syncthreads();
        if (w == r) {
            #pragma unroll
            for (int i = 0; i < 8; ++i) {
                rA[h0_ * 128 + i * 16 + s_] = gagg0[i];
                rA[h1_ * 128 + i * 16 + s_] = gagg1[i];
            }
        }
        __syncthreads();
        if (w == r - 1) {
            #pragma unroll
            for (int i = 0; i < 8; ++i) {
                gagg0[i] = f4add(gagg0[i], rA[h0_ * 128 + i * 16 + s_]);
                gagg1[i] = f4add(gagg1[i], rA[h1_ * 128 + i * 16 + s_]);
            }
        }
    }

    if (w == 0) {
        float4* pgb = (float4*)pg + (size_t)blk * 1024;
        #pragma unroll
        for (int i = 0; i < 8; ++i) {
            pgb[h0_ * 128 + i * 16 + s_] = gagg0[i];
            pgb[h1_ * 128 + i * 16 + s_] = gagg1[i];
        }
        float4 xa = f4add(f4add(xvm[h0_ * 16 + s_],       xvm[128 + h0_ * 16 + s_]),
                          f4add(xvm[256 + h0_ * 16 + s_], xvm[384 + h0_ * 16 + s_]));
        float4 xb = f4add(f4add(xvm[h1_ * 16 + s_],       xvm[128 + h1_ * 16 + s_]),
                          f4add(xvm[256 + h1_ * 16 + s_], xvm[384 + h1_ * 16 + s_]));
        float4* pxb = (float4*)pxv + (size_t)blk * 128;
        pxb[h0_ * 16 + s_] = xa;
        pxb[h1_ * 16 + s_] = xb;
        if (s_ == 0) {
            pm[blk * 8 + h0_] = M0; pm[blk * 8 + h1_] = M1;
            pl[blk * 8 + h0_] = L0; pl[blk * 8 + h1_] = L1;
        }
    }
}

// ---------------- kM: merge 4 partials + wrv GEMV epilogue ----------------
// grid 1024 = bid x 2 output-halves; block 256 (exp2 domain)
__global__ __launch_bounds__(256) void kM(
    const float* __restrict__ pg, const float* __restrict__ pxv,
    const float* __restrict__ pm, const float* __restrict__ pl,
    const float* __restrict__ wrv, const float* __restrict__ brv,
    float* __restrict__ om)
{
    __shared__ float4 gc[512];
    __shared__ float xvs[256];
    __shared__ float wexp[16], Ls[4];
    const int t = threadIdx.x;
    const int blk = blockIdx.x;
    const int bid = blk >> 1;
    const int half = blk & 1;
    const int h0 = half * 4;
    __shared__ float mlds[16], llds[16];
    if (t < 16) {
        const int i = t >> 2, hh = t & 3;
        mlds[t] = pm[bid * 32 + i * 8 + h0 + hh];
        llds[t] = pl[bid * 32 + i * 8 + h0 + hh];
    }
    __syncthreads();
    if (t < 4) {
        float M = mlds[t];
        #pragma unroll
        for (int i = 1; i < 4; ++i) M = fmaxf(M, mlds[i * 4 + t]);
        float L = 0;
        #pragma unroll
        for (int i = 0; i < 4; ++i) {
            const float wv = exp2f(mlds[i * 4 + t] - M);
            wexp[i * 4 + t] = wv;
            L += wv * llds[i * 4 + t];
        }
        Ls[t] = L;
    }
    __syncthreads();
    const int c4 = t & 127;
    #pragma unroll
    for (int r = 0; r < 2; ++r) {
        const int hh = (t >> 7) * 2 + r;
        float4 acc = {0, 0, 0, 0};
        #pragma unroll
        for (int i = 0; i < 4; ++i) {
            const float wv = wexp[i * 4 + hh];
            const float4 g = ((const float4*)pg)[((size_t)bid * 4 + i) * 1024 + (size_t)(h0 + hh) * 128 + c4];
            acc.x += wv * g.x; acc.y += wv * g.y; acc.z += wv * g.z; acc.w += wv * g.w;
        }
        gc[hh * 128 + c4] = acc;
    }
    {
        const int hh = t >> 6;
        float s = 0;
        #pragma unroll
        for (int i = 0; i < 4; ++i)
            s += wexp[i * 4 + hh] * pxv[((size_t)bid * 4 + i) * DD + half * 256 + t];
        xvs[t] = s;
    }
    __syncthreads();
    const int o = half * 256 + t;
    const int hl = t >> 6;
    const float4* wr4 = (const float4*)(wrv + (size_t)o * DD);
    float acc = 0;
    #pragma unroll 4
    for (int e4 = 0; e4 < 128; ++e4) acc += dot4(wr4[e4], gc[hl * 128 + e4]);
    om[(size_t)bid * DD + o] = (xvs[t] + acc) / Ls[hl] + brv[o];
}

// ---------------- kE ----------------
__global__ __launch_bounds__(256) void kE(
    const float* __restrict__ xl, const float* __restrict__ xr,
    float* __restrict__ ng)
{
    const int t = threadIdx.x;
    const int blk = blockIdx.x;
    const int bid = blk >> 2;
    const int yc = blk & 3;
    const int b = bid >> 8;
    const int o4 = t & 127;
    const int yh = t >> 7;
    const float4 left = ((const float4*)xl)[(size_t)bid * 128 + o4];
    const float4* xr4 = (const float4*)xr + (size_t)b * NN * 128;
    f4raw* out4 = (f4raw*)ng + (size_t)bid * NN * 128;
    for (int y = yc * 64 + yh; y < yc * 64 + 64; y += 2) {
        const float4 rr = xr4[y * 128 + o4];
        f4raw s;
        s.x = left.x + rr.x; s.y = left.y + rr.y;
        s.z = left.z + rr.z; s.w = left.w + rr.w;
        __builtin_nontemporal_store(s, &out4[y * 128 + o4]);
    }
}

extern "C" void kernel_launch(void* const* d_in, const int* in_sizes, int n_in,
                              void* d_out, int out_size, void* d_ws, size_t ws_size,
                              hipStream_t stream)
{
    (void)in_sizes; (void)n_in; (void)out_size; (void)ws_size;
    const float* x    = (const float*)d_in[0];
    const float* G    = (const float*)d_in[1];
    const unsigned char* mask = (const unsigned char*)d_in[2];
    const float* wq  = (const float*)d_in[3];  const float* bq  = (const float*)d_in[4];
    const float* wk  = (const float*)d_in[5];  const float* bk  = (const float*)d_in[6];
    const float* wv  = (const float*)d_in[7];  const float* bv  = (const float*)d_in[8];
    const float* wo  = (const float*)d_in[9];  const float* bo  = (const float*)d_in[10];
    const float* wl  = (const float*)d_in[11]; const float* bl  = (const float*)d_in[12];
    const float* wr  = (const float*)d_in[13]; const float* br  = (const float*)d_in[14];
    const float* wrk = (const float*)d_in[15]; /* brk unused: softmax-invariant */
    const float* wrv = (const float*)d_in[17]; const float* brv = (const float*)d_in[18];

    float* out  = (float*)d_out;
    float* fout = out;                          // [B,N,D]
    float* ng   = out + (size_t)BB * NN * DD;   // [B,N,N,D]

    const size_t ng_f  = (size_t)BB * NN * NN * DD;
    const size_t row_f = (size_t)BB * NN * DD;
    const size_t total = row_f * 52 + 32768;
    float* base = ng + ng_f - total;
    float* q    = base;
    float* k    = q   + row_f;
    float* vv_  = k   + row_f;
    float* qkp  = vv_ + row_f;          // row_f * 8
    float* skp  = qkp + row_f * 8;      // row_f * 4
    float* pg   = skp + row_f * 4;      // row_f * 32
    float* pxv  = pg  + row_f * 32;     // row_f * 4
    float* pm   = pxv + row_f * 4;      // 16384
    float* pl   = pm  + 16384;          // 16384
    float* om   = pl  + 16384;          // row_f
    float* xl = (float*)d_ws;
    float* xr = xl + row_f;

    kProj<<<768, 64, 0, stream>>>(x, wq, bq, wk, bk, wv, bv, q, k, vv_);
    kQS  <<<4096, 256, 0, stream>>>(q, wrk, k, mask, qkp, skp);
    kC   <<<2048, 256, 0, stream>>>(G, skp, qkp, vv_, pg, pxv, pm, pl);
    kM   <<<1024, 256, 0, stream>>>(pg, pxv, pm, pl, wrv, brv, om);
    kProj<<<768, 64, 0, stream>>>(om, wo, bo, wl, bl, wr, br, fout, xl, xr);
    kE   <<<2048, 256, 0, stream>>>(xl, xr, ng);
}

// Round 15
// 294.651 us; speedup vs baseline: 1.0470x; 1.0381x over previous
//
#include <hip/hip_runtime.h>

#define BB 2
#define NN 256
#define DD 512
#define HH 8

// 0.125 * log2(e): scores are kept in the exp2 domain end-to-end.
#define SCL 0.18033688f

typedef float f4raw __attribute__((ext_vector_type(4)));

__device__ __forceinline__ float dot4(float4 a, float4 b) {
    return a.x*b.x + a.y*b.y + a.z*b.z + a.w*b.w;
}

__device__ __forceinline__ float4 f4fma(float s, float4 a, float4 acc) {
    acc.x += s * a.x; acc.y += s * a.y; acc.z += s * a.z; acc.w += s * a.w;
    return acc;
}

__device__ __forceinline__ float4 f4mul(float s, float4 a) {
    a.x *= s; a.y *= s; a.z *= s; a.w *= s; return a;
}

__device__ __forceinline__ float4 f4add(float4 a, float4 b) {
    a.x += b.x; a.y += b.y; a.z += b.z; a.w += b.w; return a;
}

__device__ __forceinline__ void gload_lds16(const void* g, void* l) {
    __builtin_amdgcn_global_load_lds(
        (const __attribute__((address_space(1))) unsigned int*)g,
        (__attribute__((address_space(3))) unsigned int*)l, 16, 0, 0);
}

// Stage 8 rows x 512 floats global->LDS with per-row XOR swizzle.
// 4-wave cooperative (qkp): dest linear, source pre-swizzled (m173).
__device__ __forceinline__ void stage_swz(const char* rowbase, float4* dst, int w, int lane) {
    #pragma unroll
    for (int j = 0; j < 4; ++j) {
        const int f0 = w * 256 + j * 64;
        const int y = f0 >> 7;
        const int c = (f0 & 127) + lane;
        gload_lds16(rowbase + (size_t)y * 2048 + ((size_t)(c ^ y) << 4), &dst[f0]);
    }
}

// ---------------- kProj: 3 linear layers, O = X @ W^T + b -----------------
// grid 1536 = 3 proj x 16 rowtiles(32) x 32 coltiles(16); block 64 (1 wave).
// BARRIER-FREE: single-wave block, LDS ordering via compiler lgkmcnt only --
// prefetch loads stay in flight across K-chunks (no vmcnt drain).
__global__ __launch_bounds__(64) void kProj(
    const float* __restrict__ in_,
    const float* __restrict__ w0, const float* __restrict__ b0,
    const float* __restrict__ w1, const float* __restrict__ b1,
    const float* __restrict__ w2, const float* __restrict__ b2,
    float* __restrict__ o0, float* __restrict__ o1, float* __restrict__ o2)
{
    __shared__ float4 xs[2][32 * 5];   // 32 rows x 4 f4 (+pad)
    __shared__ float4 ws[2][16 * 5];   // 16 cols x 4 f4 (+pad)

    const int t = threadIdx.x;
    const int blk = blockIdx.x;
    const int proj = blk >> 9;
    const int rem = blk & 511;
    const int row0 = (rem >> 5) * 32;
    const int col0 = (rem & 31) * 16;

    const float* W; const float* Bp; float* O;
    if (proj == 0)      { W = w0; Bp = b0; O = o0; }
    else if (proj == 1) { W = w1; Bp = b1; O = o1; }
    else                { W = w2; Bp = b2; O = o2; }

    const float4* X4 = (const float4*)in_ + (size_t)row0 * 128;
    const float4* W4 = (const float4*)W  + (size_t)col0 * 128;

    const int sr = t >> 2, se = t & 3;      // staging: xs rows sr, sr+16; ws row sr
    const int ty = t >> 3, tx = t & 7;      // compute: 8x8 lane grid

    // prefetch chunk 0
    float4 rx0 = X4[(size_t)sr * 128 + se];
    float4 rx1 = X4[(size_t)(sr + 16) * 128 + se];
    float4 rw0 = W4[(size_t)(sr & 15) * 128 + se];   // sr<16 half stages ws; both halves load same -> only sr<16 writes
    xs[0][sr * 5 + se] = rx0;
    xs[0][(sr + 16) * 5 + se] = rx1;
    if (sr < 16) ws[0][sr * 5 + se] = rw0;

    float acc[4][2] = {};

    for (int q = 0; q < 32; ++q) {
        const int cur = q & 1;
        if (q < 31) {
            const int ko = (q + 1) * 4;
            rx0 = X4[(size_t)sr * 128 + ko + se];
            rx1 = X4[(size_t)(sr + 16) * 128 + ko + se];
            rw0 = W4[(size_t)(sr & 15) * 128 + ko + se];
        }
        const float4* xb = xs[cur];
        const float4* wb = ws[cur];
        #pragma unroll
        for (int e4 = 0; e4 < 4; ++e4) {
            float4 xr[4], wc[2];
            #pragma unroll
            for (int i = 0; i < 4; ++i) xr[i] = xb[(ty + 8 * i) * 5 + e4];
            #pragma unroll
            for (int j = 0; j < 2; ++j) wc[j] = wb[(tx + 8 * j) * 5 + e4];
            #pragma unroll
            for (int i = 0; i < 4; ++i)
                #pragma unroll
                for (int j = 0; j < 2; ++j)
                    acc[i][j] += dot4(xr[i], wc[j]);
        }
        if (q < 31) {
            const int nxt = cur ^ 1;
            xs[nxt][sr * 5 + se] = rx0;
            xs[nxt][(sr + 16) * 5 + se] = rx1;
            if (sr < 16) ws[nxt][sr * 5 + se] = rw0;
        }
    }

    const float b0v = Bp[col0 + tx];
    const float b1v = Bp[col0 + tx + 8];
    #pragma unroll
    for (int i = 0; i < 4; ++i) {
        const int orow = row0 + ty + 8 * i;
        O[(size_t)orow * DD + col0 + tx]     = acc[i][0] + b0v;
        O[(size_t)orow * DD + col0 + tx + 8] = acc[i][1] + b1v;
    }
}

// ---------------- kQS: fused kQkp (blocks 0..2047) + kSk (2048..4095) -----
__global__ __launch_bounds__(256) void kQS(
    const float* __restrict__ q, const float* __restrict__ wrk,
    const float* __restrict__ k, const unsigned char* __restrict__ mask,
    float* __restrict__ qkp, float* __restrict__ sk)
{
    __shared__ float sm[4680];
    const int t = threadIdx.x;
    const int blk0 = blockIdx.x;

    if (blk0 < 2048) {
        float* qs = sm;
        const int rowg = blk0 >> 5;
        const int h = (blk0 >> 2) & 7;
        const int eq = blk0 & 3;
        const int row0 = rowg * 8;
        {
            const int r = t >> 5, d2 = (t & 31) * 2;
            const float2 tmp = *(const float2*)(q + (size_t)(row0 + r) * DD + h * 64 + d2);
            qs[r * 64 + d2] = tmp.x; qs[r * 64 + d2 + 1] = tmp.y;
        }
        __syncthreads();
        const int e = eq * 128 + (t & 127);
        const int rp = (t >> 7) * 4;
        const float* wcol = wrk + (size_t)(h * 64) * DD + e;
        float a0 = 0, a1 = 0, a2 = 0, a3 = 0;
        #pragma unroll 8
        for (int d = 0; d < 64; ++d) {
            const float wv = wcol[(size_t)d * DD];
            a0 += qs[(rp + 0) * 64 + d] * wv;
            a1 += qs[(rp + 1) * 64 + d] * wv;
            a2 += qs[(rp + 2) * 64 + d] * wv;
            a3 += qs[(rp + 3) * 64 + d] * wv;
        }
        qkp[((size_t)(row0 + rp + 0) * HH + h) * DD + e] = a0;
        qkp[((size_t)(row0 + rp + 1) * HH + h) * DD + e] = a1;
        qkp[((size_t)(row0 + rp + 2) * HH + h) * DD + e] = a2;
        qkp[((size_t)(row0 + rp + 3) * HH + h) * DD + e] = a3;
    } else {
        const int blk = blk0 - 2048;
        float* qs = sm;
        float* ks = sm + 8 * 65;
        const int b  = blk >> 10;
        const int h  = (blk >> 7) & 7;
        const int xt = (blk >> 2) & 31;
        const int yt = blk & 3;
        const int x0 = xt * 8, y0 = yt * 64;
        {
            const int r = t >> 5, d2 = (t & 31) * 2;
            const float2 tmp = *(const float2*)(q + (size_t)(b * NN + x0 + r) * DD + h * 64 + d2);
            qs[r * 65 + d2] = tmp.x; qs[r * 65 + d2 + 1] = tmp.y;
        }
        #pragma unroll
        for (int j = 0; j < 8; ++j) {
            const int f = t + 256 * j;
            const int r = f >> 5, d2 = (f & 31) * 2;
            const float2 tmp = *(const float2*)(k + (size_t)(b * NN + y0 + r) * DD + h * 64 + d2);
            ks[r * 65 + d2] = tmp.x; ks[r * 65 + d2 + 1] = tmp.y;
        }
        __syncthreads();
        const int xi = t >> 5, yg = t & 31;
        float a0 = 0, a1 = 0;
        #pragma unroll 8
        for (int d = 0; d < 64; ++d) {
            const float qv = qs[xi * 65 + d];
            a0 += qv * ks[(yg * 2 + 0) * 65 + d];
            a1 += qv * ks[(yg * 2 + 1) * 65 + d];
        }
        a0 *= SCL; a1 *= SCL;
        const unsigned char* mrow = mask + (size_t)(b * NN + x0 + xi) * NN;
        const int gy = y0 + yg * 2;
        if (mrow[gy + 0]) a0 = -1e9f;
        if (mrow[gy + 1]) a1 = -1e9f;
        float2 st; st.x = a0; st.y = a1;
        *(float2*)(sk + ((size_t)(b * NN + x0 + xi) * HH + h) * NN + gy) = st;
    }
}

// ---------------- kC: G-in-REGISTERS flash attention, split-K4 -----------
// grid 2048 = (b*N) x 4 parts; block 256 = 4 waves; 8 tiles of 8 y-rows.
__global__ __launch_bounds__(256) void kC(
    const float* __restrict__ G, const float* __restrict__ sk,
    const float* __restrict__ qkp, const float* __restrict__ v,
    float* __restrict__ pg, float* __restrict__ pxv,
    float* __restrict__ pm, float* __restrict__ pl)
{
    __shared__ float4 qk4[1024];   // qkp [8h][128] swizzled ^h; merge scratch later
    __shared__ float4 xvm[512];    // per-wave xv partials [w][h*16+s_]
    __shared__ float  sk_lds[512]; // [ry 0..63][h 0..7]; ml overlay later

    const int t = threadIdx.x;
    const int lane = t & 63;
    const int w = t >> 6;
    const int blk = blockIdx.x;
    const int part = blk & 3;
    const int bid = blk >> 2;
    const int b = bid >> 8;
    const int ybase = part * 64;

    const int s_ = lane & 15;
    const int g  = lane >> 4;
    const int h0_ = 2 * g, h1_ = h0_ + 1;
    const int yr0 = 2 * w, yr1 = yr0 + 1;

    const float4* Gb4 = (const float4*)(G + (size_t)bid * NN * DD);
    const float* skb = sk + (size_t)bid * HH * NN;
    const float4* vb4 = (const float4*)(v + (size_t)(b * NN) * DD);

    // ---- prologue: qkp -> LDS (staged), sk -> LDS ----
    const int f0p = 2 * t, f1p = 2 * t + 1;
    const float skv0 = skb[(f0p & 7) * NN + ybase + (f0p >> 3)];
    const float skv1 = skb[(f1p & 7) * NN + ybase + (f1p >> 3)];
    stage_swz((const char*)(qkp + (size_t)bid * HH * DD), qk4, w, lane);
    sk_lds[f0p] = skv0;
    sk_lds[f1p] = skv1;
    __syncthreads();   // drains vmcnt: qkp ready

    float4 gagg0[8], gagg1[8];
    #pragma unroll
    for (int i = 0; i < 8; ++i) {
        gagg0[i] = make_float4(0, 0, 0, 0);
        gagg1[i] = make_float4(0, 0, 0, 0);
    }
    float4 xv0 = {0, 0, 0, 0}, xv1 = {0, 0, 0, 0};
    float m0_ = -3e38f, m1_ = -3e38f, l0_ = 0.f, l1_ = 0.f;

    #pragma unroll 1
    for (int tt = 0; tt < 8; ++tt) {
        const int gy0 = ybase + tt * 8 + yr0;
        const int gy1 = gy0 + 1;
        const int ry0 = tt * 8 + yr0, ry1 = ry0 + 1;

        float4 g0[8], g1[8];
        #pragma unroll
        for (int i = 0; i < 8; ++i) g0[i] = Gb4[(size_t)gy0 * 128 + i * 16 + s_];
        #pragma unroll
        for (int i = 0; i < 8; ++i) g1[i] = Gb4[(size_t)gy1 * 128 + i * 16 + s_];
        const float4 v00 = vb4[(size_t)gy0 * 128 + h0_ * 16 + s_];
        const float4 v01 = vb4[(size_t)gy0 * 128 + h1_ * 16 + s_];
        const float4 v10 = vb4[(size_t)gy1 * 128 + h0_ * 16 + s_];
        const float4 v11 = vb4[(size_t)gy1 * 128 + h1_ * 16 + s_];

        float a00 = 0, a01 = 0, a10 = 0, a11 = 0;
        #pragma unroll
        for (int i = 0; i < 8; ++i) {
            const int e4 = i * 16 + s_;
            const float4 q0 = qk4[h0_ * 128 + (e4 ^ h0_)];
            const float4 q1 = qk4[h1_ * 128 + (e4 ^ h1_)];
            a00 += dot4(g0[i], q0); a01 += dot4(g0[i], q1);
            a10 += dot4(g1[i], q0); a11 += dot4(g1[i], q1);
        }
        #pragma unroll
        for (int mm = 1; mm < 16; mm <<= 1) {
            a00 += __shfl_xor(a00, mm); a01 += __shfl_xor(a01, mm);
            a10 += __shfl_xor(a10, mm); a11 += __shfl_xor(a11, mm);
        }
        const float s00 = a00 * SCL + sk_lds[ry0 * 8 + h0_];
        const float s01 = a01 * SCL + sk_lds[ry0 * 8 + h1_];
        const float s10 = a10 * SCL + sk_lds[ry1 * 8 + h0_];
        const float s11 = a11 * SCL + sk_lds[ry1 * 8 + h1_];

        const float mn0 = fmaxf(m0_, fmaxf(s00, s10));
        const float rs0 = exp2f(m0_ - mn0);
        const float p00 = exp2f(s00 - mn0), p10 = exp2f(s10 - mn0);
        m0_ = mn0; l0_ = l0_ * rs0 + p00 + p10;
        const float mn1 = fmaxf(m1_, fmaxf(s01, s11));
        const float rs1 = exp2f(m1_ - mn1);
        const float p01 = exp2f(s01 - mn1), p11 = exp2f(s11 - mn1);
        m1_ = mn1; l1_ = l1_ * rs1 + p01 + p11;

        #pragma unroll
        for (int i = 0; i < 8; ++i) {
            gagg0[i] = f4fma(p10, g1[i], f4fma(p00, g0[i], f4mul(rs0, gagg0[i])));
            gagg1[i] = f4fma(p11, g1[i], f4fma(p01, g0[i], f4mul(rs1, gagg1[i])));
        }
        xv0 = f4fma(p10, v10, f4fma(p00, v00, f4mul(rs0, xv0)));
        xv1 = f4fma(p11, v11, f4fma(p01, v01, f4mul(rs1, xv1)));
    }

    // ---- epilogue: merge 4 wave partials ----
    __syncthreads();
    float* ml = sk_lds;   // overlay (sk_lds dead)
    if (s_ == 0) {
        ml[w * 16 + h0_] = m0_;      ml[w * 16 + h1_] = m1_;
        ml[w * 16 + 8 + h0_] = l0_;  ml[w * 16 + 8 + h1_] = l1_;
    }
    __syncthreads();

    float M0, M1, L0, L1;
    {
        const float q0 = ml[h0_], q1 = ml[16 + h0_], q2 = ml[32 + h0_], q3 = ml[48 + h0_];
        M0 = fmaxf(fmaxf(q0, q1), fmaxf(q2, q3));
        L0 = exp2f(q0 - M0) * ml[8 + h0_]  + exp2f(q1 - M0) * ml[24 + h0_]
           + exp2f(q2 - M0) * ml[40 + h0_] + exp2f(q3 - M0) * ml[56 + h0_];
        const float r0 = ml[h1_], r1 = ml[16 + h1_], r2 = ml[32 + h1_], r3 = ml[48 + h1_];
        M1 = fmaxf(fmaxf(r0, r1), fmaxf(r2, r3));
        L1 = exp2f(r0 - M1) * ml[8 + h1_]  + exp2f(r1 - M1) * ml[24 + h1_]
           + exp2f(r2 - M1) * ml[40 + h1_] + exp2f(r3 - M1) * ml[56 + h1_];
    }
    const float e0 = exp2f(m0_ - M0), e1 = exp2f(m1_ - M1);
    #pragma unroll
    for (int i = 0; i < 8; ++i) {
        gagg0[i] = f4mul(e0, gagg0[i]);
        gagg1[i] = f4mul(e1, gagg1[i]);
    }
    xv0 = f4mul(e0, xv0); xv1 = f4mul(e1, xv1);

    xvm[w * 128 + h0_ * 16 + s_] = xv0;
    xvm[w * 128 + h1_ * 16 + s_] = xv1;

    float4* rA = qk4;   // qkp dead: merge scratch (1024 f4)
    #pragma unroll 1
    for (int r = 3; r >= 1; --r) {
        __syncthreads();
        if (w == r) {
            #pragma unroll
            for (int i = 0; i < 8; ++i) {
                rA[h0_ * 128 + i * 16 + s_] = gagg0[i];
                rA[h1_ * 128 + i * 16 + s_] = gagg1[i];
            }
        }
        __syncthreads();
        if (w == r - 1) {
            #pragma unroll
            for (int i = 0; i < 8; ++i) {
                gagg0[i] = f4add(gagg0[i], rA[h0_ * 128 + i * 16 + s_]);
                gagg1[i] = f4add(gagg1[i], rA[h1_ * 128 + i * 16 + s_]);
            }
        }
    }

    if (w == 0) {
        float4* pgb = (float4*)pg + (size_t)blk * 1024;
        #pragma unroll
        for (int i = 0; i < 8; ++i) {
            pgb[h0_ * 128 + i * 16 + s_] = gagg0[i];
            pgb[h1_ * 128 + i * 16 + s_] = gagg1[i];
        }
        float4 xa = f4add(f4add(xvm[h0_ * 16 + s_],       xvm[128 + h0_ * 16 + s_]),
                          f4add(xvm[256 + h0_ * 16 + s_], xvm[384 + h0_ * 16 + s_]));
        float4 xb = f4add(f4add(xvm[h1_ * 16 + s_],       xvm[128 + h1_ * 16 + s_]),
                          f4add(xvm[256 + h1_ * 16 + s_], xvm[384 + h1_ * 16 + s_]));
        float4* pxb = (float4*)pxv + (size_t)blk * 128;
        pxb[h0_ * 16 + s_] = xa;
        pxb[h1_ * 16 + s_] = xb;
        if (s_ == 0) {
            pm[blk * 8 + h0_] = M0; pm[blk * 8 + h1_] = M1;
            pl[blk * 8 + h0_] = L0; pl[blk * 8 + h1_] = L1;
        }
    }
}

// ---------------- kM: merge 4 partials + wrv GEMV epilogue ----------------
// grid 1024 = bid x 2 output-halves; block 256 (exp2 domain)
__global__ __launch_bounds__(256) void kM(
    const float* __restrict__ pg, const float* __restrict__ pxv,
    const float* __restrict__ pm, const float* __restrict__ pl,
    const float* __restrict__ wrv, const float* __restrict__ brv,
    float* __restrict__ om)
{
    __shared__ float4 gc[512];
    __shared__ float xvs[256];
    __shared__ float wexp[16], Ls[4];
    const int t = threadIdx.x;
    const int blk = blockIdx.x;
    const int bid = blk >> 1;
    const int half = blk & 1;
    const int h0 = half * 4;
    __shared__ float mlds[16], llds[16];
    if (t < 16) {
        const int i = t >> 2, hh = t & 3;
        mlds[t] = pm[bid * 32 + i * 8 + h0 + hh];
        llds[t] = pl[bid * 32 + i * 8 + h0 + hh];
    }
    __syncthreads();
    if (t < 4) {
        float M = mlds[t];
        #pragma unroll
        for (int i = 1; i < 4; ++i) M = fmaxf(M, mlds[i * 4 + t]);
        float L = 0;
        #pragma unroll
        for (int i = 0; i < 4; ++i) {
            const float wv = exp2f(mlds[i * 4 + t] - M);
            wexp[i * 4 + t] = wv;
            L += wv * llds[i * 4 + t];
        }
        Ls[t] = L;
    }
    __syncthreads();
    const int c4 = t & 127;
    #pragma unroll
    for (int r = 0; r < 2; ++r) {
        const int hh = (t >> 7) * 2 + r;
        float4 acc = {0, 0, 0, 0};
        #pragma unroll
        for (int i = 0; i < 4; ++i) {
            const float wv = wexp[i * 4 + hh];
            const float4 g = ((const float4*)pg)[((size_t)bid * 4 + i) * 1024 + (size_t)(h0 + hh) * 128 + c4];
            acc.x += wv * g.x; acc.y += wv * g.y; acc.z += wv * g.z; acc.w += wv * g.w;
        }
        gc[hh * 128 + c4] = acc;
    }
    {
        const int hh = t >> 6;
        float s = 0;
        #pragma unroll
        for (int i = 0; i < 4; ++i)
            s += wexp[i * 4 + hh] * pxv[((size_t)bid * 4 + i) * DD + half * 256 + t];
        xvs[t] = s;
    }
    __syncthreads();
    const int o = half * 256 + t;
    const int hl = t >> 6;
    const float4* wr4 = (const float4*)(wrv + (size_t)o * DD);
    float acc = 0;
    #pragma unroll 4
    for (int e4 = 0; e4 < 128; ++e4) acc += dot4(wr4[e4], gc[hl * 128 + e4]);
    om[(size_t)bid * DD + o] = (xvs[t] + acc) / Ls[hl] + brv[o];
}

// ---------------- kE: grid 8192 = 512 bid x 16 y-chunks; block 256 -------
__global__ __launch_bounds__(256) void kE(
    const float* __restrict__ xl, const float* __restrict__ xr,
    float* __restrict__ ng)
{
    const int t = threadIdx.x;
    const int blk = blockIdx.x;
    const int bid = blk >> 4;
    const int yc = blk & 15;
    const int b = bid >> 8;
    const int o4 = t & 127;
    const int yh = t >> 7;
    const float4 left = ((const float4*)xl)[(size_t)bid * 128 + o4];
    const float4* xr4 = (const float4*)xr + (size_t)b * NN * 128;
    f4raw* out4 = (f4raw*)ng + (size_t)bid * NN * 128;
    #pragma unroll
    for (int i = 0; i < 8; ++i) {
        const int y = yc * 16 + i * 2 + yh;
        const float4 rr = xr4[y * 128 + o4];
        f4raw s;
        s.x = left.x + rr.x; s.y = left.y + rr.y;
        s.z = left.z + rr.z; s.w = left.w + rr.w;
        __builtin_nontemporal_store(s, &out4[y * 128 + o4]);
    }
}

extern "C" void kernel_launch(void* const* d_in, const int* in_sizes, int n_in,
                              void* d_out, int out_size, void* d_ws, size_t ws_size,
                              hipStream_t stream)
{
    (void)in_sizes; (void)n_in; (void)out_size; (void)ws_size;
    const float* x    = (const float*)d_in[0];
    const float* G    = (const float*)d_in[1];
    const unsigned char* mask = (const unsigned char*)d_in[2];
    const float* wq  = (const float*)d_in[3];  const float* bq  = (const float*)d_in[4];
    const float* wk  = (const float*)d_in[5];  const float* bk  = (const float*)d_in[6];
    const float* wv  = (const float*)d_in[7];  const float* bv  = (const float*)d_in[8];
    const float* wo  = (const float*)d_in[9];  const float* bo  = (const float*)d_in[10];
    const float* wl  = (const float*)d_in[11]; const float* bl  = (const float*)d_in[12];
    const float* wr  = (const float*)d_in[13]; const float* br  = (const float*)d_in[14];
    const float* wrk = (const float*)d_in[15]; /* brk unused: softmax-invariant */
    const float* wrv = (const float*)d_in[17]; const float* brv = (const float*)d_in[18];

    float* out  = (float*)d_out;
    float* fout = out;                          // [B,N,D]
    float* ng   = out + (size_t)BB * NN * DD;   // [B,N,N,D]

    const size_t ng_f  = (size_t)BB * NN * NN * DD;
    const size_t row_f = (size_t)BB * NN * DD;
    const size_t total = row_f * 52 + 32768;
    float* base = ng + ng_f - total;
    float* q    = base;
    float* k    = q   + row_f;
    float* vv_  = k   + row_f;
    float* qkp  = vv_ + row_f;          // row_f * 8
    float* skp  = qkp + row_f * 8;      // row_f * 4
    float* pg   = skp + row_f * 4;      // row_f * 32
    float* pxv  = pg  + row_f * 32;     // row_f * 4
    float* pm   = pxv + row_f * 4;      // 16384
    float* pl   = pm  + 16384;          // 16384
    float* om   = pl  + 16384;          // row_f
    float* xl = (float*)d_ws;
    float* xr = xl + row_f;

    kProj<<<1536, 64, 0, stream>>>(x, wq, bq, wk, bk, wv, bv, q, k, vv_);
    kQS  <<<4096, 256, 0, stream>>>(q, wrk, k, mask, qkp, skp);
    kC   <<<2048, 256, 0, stream>>>(G, skp, qkp, vv_, pg, pxv, pm, pl);
    kM   <<<1024, 256, 0, stream>>>(pg, pxv, pm, pl, wrv, brv, om);
    kProj<<<1536, 64, 0, stream>>>(om, wo, bo, wl, bl, wr, br, fout, xl, xr);
    kE   <<<8192, 256, 0, stream>>>(xl, xr, ng);
}